// Round 4
// baseline (579.932 us; speedup 1.0000x reference)
//
#include <hip/hip_runtime.h>
#include <stdint.h>

#define N_ROWS 65536
#define DIM    1000
#define KCB    256

// ---------------- old (proven) path: kept as fallback if ws_size is small ----------------
#define RB     64
#define DT     32
#define PITCH  36

__global__ __launch_bounds__(256) void wsq_old_kernel(const float* __restrict__ w,
                                                      float* __restrict__ wsq) {
    const int wave = threadIdx.x >> 6;
    const int lane = threadIdx.x & 63;
    const int k = blockIdx.x * 4 + wave;
    double s = 0.0;
    for (int c = lane; c < DIM / 4; c += 64) {
        const float4 v = *(const float4*)(w + k * DIM + c * 4);
        s += (double)v.x * v.x + (double)v.y * v.y + (double)v.z * v.z + (double)v.w * v.w;
    }
    #pragma unroll
    for (int off = 32; off; off >>= 1) s += __shfl_down(s, off, 64);
    if (lane == 0) wsq[k] = (float)s;
}

__global__ __launch_bounds__(256) void xsq_old_kernel(const float* __restrict__ x,
                                                      float* __restrict__ xsq) {
    const int wave = threadIdx.x >> 6;
    const int lane = threadIdx.x & 63;
    const int row = blockIdx.x * 4 + wave;
    double s = 0.0;
    for (int c = lane; c < DIM / 4; c += 64) {
        const float4 v = *(const float4*)(x + (size_t)row * DIM + c * 4);
        s += (double)v.x * v.x + (double)v.y * v.y + (double)v.z * v.z + (double)v.w * v.w;
    }
    #pragma unroll
    for (int off = 32; off; off >>= 1) s += __shfl_down(s, off, 64);
    if (lane == 0) xsq[row] = (float)s;
}

__global__ __launch_bounds__(256) void vq_old_kernel(const float* __restrict__ x,
                                                     const float* __restrict__ w,
                                                     const float* __restrict__ wsq,
                                                     const float* __restrict__ xsq,
                                                     float* __restrict__ out) {
    __shared__ float Xs[RB * PITCH];
    __shared__ float Ws[KCB * PITCH];
    __shared__ int   lidx[RB];

    const int tid  = threadIdx.x;
    const int row0 = blockIdx.x * RB;
    const int kt = tid & 31;
    const int rt = tid >> 5;

    double acc[8][8];
    #pragma unroll
    for (int i = 0; i < 8; i++)
        #pragma unroll
        for (int j = 0; j < 8; j++) acc[i][j] = 0.0;

    const int wk = tid >> 3;
    const int wg = tid & 7;
    const int xr = tid >> 2;
    const int xg = tid & 3;

    for (int d0 = 0; d0 < DIM; d0 += DT) {
        #pragma unroll
        for (int p = 0; p < 8; p++) {
            const int k = p * 32 + wk;
            const int d = d0 + wg * 4;
            float4 v = make_float4(0.f, 0.f, 0.f, 0.f);
            if (d < DIM) v = *(const float4*)(w + k * DIM + d);
            *(float4*)(&Ws[k * PITCH + wg * 4]) = v;
        }
        #pragma unroll
        for (int p = 0; p < 2; p++) {
            const int off = (xg + p * 4) * 4;
            const int d = d0 + off;
            float4 v = make_float4(0.f, 0.f, 0.f, 0.f);
            if (d < DIM) v = *(const float4*)(x + (size_t)(row0 + xr) * DIM + d);
            *(float4*)(&Xs[xr * PITCH + off]) = v;
        }
        __syncthreads();

        #pragma unroll
        for (int dq = 0; dq < DT; dq += 4) {
            float4 xf[8], wf[8];
            #pragma unroll
            for (int i = 0; i < 8; i++)
                xf[i] = *(const float4*)(&Xs[(rt + 8 * i) * PITCH + dq]);
            #pragma unroll
            for (int j = 0; j < 8; j++)
                wf[j] = *(const float4*)(&Ws[(kt + 32 * j) * PITCH + dq]);
            #pragma unroll
            for (int i = 0; i < 8; i++)
                #pragma unroll
                for (int j = 0; j < 8; j++) {
                    float p = xf[i].x * wf[j].x;
                    p = fmaf(xf[i].y, wf[j].y, p);
                    p = fmaf(xf[i].z, wf[j].z, p);
                    p = fmaf(xf[i].w, wf[j].w, p);
                    acc[i][j] += (double)p;
                }
        }
        __syncthreads();
    }

    #pragma unroll
    for (int i = 0; i < 8; i++) {
        const float xs = xsq[row0 + rt + 8 * i];
        float bestv = 3.4e38f;
        int   bestk = 0;
        #pragma unroll
        for (int j = 0; j < 8; j++) {
            const int k = kt + 32 * j;
            const float c32 = (float)acc[i][j];
            const float t1  = xs - 2.0f * c32;
            const float s   = t1 + wsq[k];
            if (s < bestv || (s == bestv && k < bestk)) { bestv = s; bestk = k; }
        }
        #pragma unroll
        for (int m = 16; m >= 1; m >>= 1) {
            const float ov = __shfl_xor(bestv, m, 64);
            const int   ok = __shfl_xor(bestk, m, 64);
            if (ov < bestv || (ov == bestv && ok < bestk)) { bestv = ov; bestk = ok; }
        }
        if (kt == 0) lidx[rt + 8 * i] = bestk;
    }
    __syncthreads();

    const int wave = tid >> 6;
    const int lane = tid & 63;
    for (int r = wave; r < RB; r += 4) {
        const int k = lidx[r];
        const float4* src = (const float4*)(w + k * DIM);
        float4* dst = (float4*)(out + (size_t)(row0 + r) * DIM);
        for (int c = lane; c < DIM / 4; c += 64) dst[c] = src[c];
    }
}

// ---------------- MFMA path ----------------
// cross(n,k) via 3 bf16 MFMA products in fp32 with SPLIT accumulators (margins as r2).
// Candidate mask per row in LDS; rows with >1 candidate resolved IN-KERNEL with the exact
// fp64-quad pipeline (verbatim math/tie-break) before the gather. Output bit-identical.
// r4: T3/T4 schedule — raw s_barrier + counted vmcnt; staging loads stay in flight
// across barriers (W staging is wave-private; only X needs cross-wave sync).

#define RBM    64       // rows per block
#define NSTEP  32       // 1024 / 32 (D padded to 1024 with zeros)
#define XHI    0
#define XLO    4096
#define WHIO   8192
#define WLOO   24576
#define LDSB   40960    // bytes per buffer (X 8KB + W 32KB)

typedef short bf16x8 __attribute__((ext_vector_type(8)));
typedef float f32x4  __attribute__((ext_vector_type(4)));
typedef unsigned short us8 __attribute__((ext_vector_type(8)));

#define SBAR()  __builtin_amdgcn_s_barrier()
#define WAITV(n) asm volatile("s_waitcnt vmcnt(" #n ")" ::: "memory")
#define WAITL()  asm volatile("s_waitcnt lgkmcnt(0)" ::: "memory")

__device__ __forceinline__ unsigned short f2bf(float f) {  // RNE float->bf16
    union { float f; unsigned int u; } v; v.f = f;
    return (unsigned short)((v.u + 0x7FFFu + ((v.u >> 16) & 1u)) >> 16);
}
__device__ __forceinline__ float bf2f(unsigned short h) {
    union { float f; unsigned int u; } v; v.u = ((unsigned int)h) << 16;
    return v.f;
}
__device__ __forceinline__ void glds16(const void* g, void* l) {
    __builtin_amdgcn_global_load_lds((const __attribute__((address_space(1))) unsigned int*)g,
                                     (__attribute__((address_space(3))) unsigned int*)l, 16, 0, 0);
}

// wsq (bitwise-identical to old) + W split into fragment-arranged bf16 hi/lo arrays.
__global__ __launch_bounds__(256) void prep_kernel(const float* __restrict__ w,
        float* __restrict__ wsq, unsigned short* __restrict__ whi, unsigned short* __restrict__ wlo) {
    const int wave = threadIdx.x >> 6;
    const int lane = threadIdx.x & 63;
    const int k = blockIdx.x * 4 + wave;
    double s = 0.0;
    for (int c = lane; c < DIM / 4; c += 64) {
        const float4 v = *(const float4*)(w + k * DIM + c * 4);
        s += (double)v.x * v.x + (double)v.y * v.y + (double)v.z * v.z + (double)v.w * v.w;
    }
    #pragma unroll
    for (int off = 32; off; off >>= 1) s += __shfl_down(s, off, 64);
    if (lane == 0) wsq[k] = (float)s;

    const int ct = k >> 4, kl = k & 15;
    for (int c = lane; c < 256; c += 64) {           // 256 quads = 1024 padded dims
        float4 v = make_float4(0.f, 0.f, 0.f, 0.f);
        if (c < DIM / 4) v = *(const float4*)(w + k * DIM + c * 4);
        ushort4 h, l;
        h.x = f2bf(v.x); l.x = f2bf(v.x - bf2f(h.x));
        h.y = f2bf(v.y); l.y = f2bf(v.y - bf2f(h.y));
        h.z = f2bf(v.z); l.z = f2bf(v.z - bf2f(h.z));
        h.w = f2bf(v.w); l.w = f2bf(v.w - bf2f(h.w));
        const int step = c >> 3, qq = c & 7;
        const int pos = step * 16384 + ct * 1024 + ((qq >> 1) * 16 + kl) * 16 + (qq & 1) * 8;
        *(ushort4*)((char*)whi + pos) = h;
        *(ushort4*)((char*)wlo + pos) = l;
    }
}

// xsq bitwise-identical to old + S1 = sum|x| (fp64) for the margin bound.
__global__ __launch_bounds__(256) void xsq_s1_kernel(const float* __restrict__ x,
        float* __restrict__ xsq, float* __restrict__ s1) {
    const int wave = threadIdx.x >> 6;
    const int lane = threadIdx.x & 63;
    const int row = blockIdx.x * 4 + wave;
    double s = 0.0, a = 0.0;
    for (int c = lane; c < DIM / 4; c += 64) {
        const float4 v = *(const float4*)(x + (size_t)row * DIM + c * 4);
        s += (double)v.x * v.x + (double)v.y * v.y + (double)v.z * v.z + (double)v.w * v.w;
        a += (double)fabsf(v.x) + (double)fabsf(v.y) + (double)fabsf(v.z) + (double)fabsf(v.w);
    }
    #pragma unroll
    for (int off = 32; off; off >>= 1) { s += __shfl_down(s, off, 64); a += __shfl_down(a, off, 64); }
    if (lane == 0) { xsq[row] = (float)s; s1[row] = (float)a; }
}

__global__ __launch_bounds__(256, 2) void vq_main_kernel(
        const float* __restrict__ x, const float* __restrict__ w,
        const float* __restrict__ wsq, const float* __restrict__ xsq,
        const float* __restrict__ s1,
        const unsigned short* __restrict__ whi, const unsigned short* __restrict__ wlo,
        float* __restrict__ out) {
    __shared__ __align__(16) char lds[2 * LDSB];   // 80 KB -> 2 blocks/CU
    const int tid  = threadIdx.x;
    const int lane = tid & 63;
    const int wv   = tid >> 6;          // code group: codes [64*wv, 64*wv+64)
    const int row0 = blockIdx.x * RBM;

    // X staging (bank-conflict-free): lane l of wave wv writes LDS byte wv*1024 + l*16.
    // Thread -> row = 16*wv + (l&15), elems 8*qp..+7, qp=(l>>4)&3.
    const int qp   = (lane >> 4) & 3;
    const int srow = wv * 16 + (lane & 15);
    const size_t xrow_off = (size_t)(row0 + srow) * DIM;
    const int xpos0 = wv * 1024 + lane * 16;

    f32x4 accm[4][4], accc[4][4];
    {
        const f32x4 z = {0.f, 0.f, 0.f, 0.f};
        #pragma unroll
        for (int i = 0; i < 4; i++)
            #pragma unroll
            for (int j = 0; j < 4; j++) { accm[i][j] = z; accc[i][j] = z; }
    }

    // two named register sets (static indexing only). Loads are UNCONDITIONAL with a
    // clamped address + select-to-zero, so the per-step VMEM-op count is uniform
    // (required by the counted-vmcnt ledger). Values match the old bounds-checked form.
    float4 xa0, xb0, xa1, xb1;
    auto xloadA = [&](int t) {
        const int dA = t * 32 + qp * 8;
        const int pA = dA > 992 ? 992 : dA;
        const int pB = dA + 4 > 996 ? 996 : dA + 4;
        xa0 = *(const float4*)(x + xrow_off + pA);
        xb0 = *(const float4*)(x + xrow_off + pB);
        if (dA > 992)     xa0 = make_float4(0.f, 0.f, 0.f, 0.f);
        if (dA + 4 > 996) xb0 = make_float4(0.f, 0.f, 0.f, 0.f);
    };
    auto xloadB = [&](int t) {
        const int dA = t * 32 + qp * 8;
        const int pA = dA > 992 ? 992 : dA;
        const int pB = dA + 4 > 996 ? 996 : dA + 4;
        xa1 = *(const float4*)(x + xrow_off + pA);
        xb1 = *(const float4*)(x + xrow_off + pB);
        if (dA > 992)     xa1 = make_float4(0.f, 0.f, 0.f, 0.f);
        if (dA + 4 > 996) xb1 = make_float4(0.f, 0.f, 0.f, 0.f);
    };
    auto xstore = [&](int b, const float4& xa, const float4& xb) {
        us8 h, l;
        h[0] = f2bf(xa.x); l[0] = f2bf(xa.x - bf2f(h[0]));
        h[1] = f2bf(xa.y); l[1] = f2bf(xa.y - bf2f(h[1]));
        h[2] = f2bf(xa.z); l[2] = f2bf(xa.z - bf2f(h[2]));
        h[3] = f2bf(xa.w); l[3] = f2bf(xa.w - bf2f(h[3]));
        h[4] = f2bf(xb.x); l[4] = f2bf(xb.x - bf2f(h[4]));
        h[5] = f2bf(xb.y); l[5] = f2bf(xb.y - bf2f(h[5]));
        h[6] = f2bf(xb.z); l[6] = f2bf(xb.z - bf2f(h[6]));
        h[7] = f2bf(xb.w); l[7] = f2bf(xb.w - bf2f(h[7]));
        *(us8*)(lds + b * LDSB + XHI + xpos0) = h;
        *(us8*)(lds + b * LDSB + XLO + xpos0) = l;
    };
    auto wstage = [&](int b, int t) {
        #pragma unroll
        for (int i = 0; i < 4; i++) {
            const int ch = wv * 4 + i;
            glds16(whi + (size_t)t * 8192 + ch * 512 + lane * 8, lds + b * LDSB + WHIO + ch * 1024);
            glds16(wlo + (size_t)t * 8192 + ch * 512 + lane * 8, lds + b * LDSB + WLOO + ch * 1024);
        }
    };
    auto compute = [&](int b) {
        const char* base = lds + b * LDSB;
        bf16x8 ahi[4], alo[4];
        #pragma unroll
        for (int rt = 0; rt < 4; rt++) {
            ahi[rt] = *(const bf16x8*)(base + XHI + rt * 1024 + lane * 16);
            alo[rt] = *(const bf16x8*)(base + XLO + rt * 1024 + lane * 16);
        }
        __builtin_amdgcn_s_setprio(1);
        #pragma unroll
        for (int jt = 0; jt < 4; jt++) {
            const int ct = wv * 4 + jt;
            const bf16x8 bhi = *(const bf16x8*)(base + WHIO + ct * 1024 + lane * 16);
            const bf16x8 blo = *(const bf16x8*)(base + WLOO + ct * 1024 + lane * 16);
            #pragma unroll
            for (int rt = 0; rt < 4; rt++) {
                accm[rt][jt] = __builtin_amdgcn_mfma_f32_16x16x32_bf16(ahi[rt], bhi, accm[rt][jt], 0, 0, 0);
                accc[rt][jt] = __builtin_amdgcn_mfma_f32_16x16x32_bf16(ahi[rt], blo, accc[rt][jt], 0, 0, 0);
                accc[rt][jt] = __builtin_amdgcn_mfma_f32_16x16x32_bf16(alo[rt], bhi, accc[rt][jt], 0, 0, 0);
            }
        }
        __builtin_amdgcn_s_setprio(0);
    };

    // ---- prologue ----
    // vmcnt ledger (per wave; W staging is wave-private so glds hazards are intra-wave;
    // X handoff is cross-wave and protected by lgkmcnt(0)+s_barrier):
    wstage(0, 0);           // queue: [s0 x8]
    xloadA(0);              // +2   (compiler drains for reg use below; prologue-only)
    xstore(0, xa0, xb0);
    xloadB(1);              // +2
    wstage(1, 1);           // +8 -> steady entry for t=0: [xl1 x2][s1 x8]
    WAITL(); SBAR();

    // ---- main loop: steady-state entry queue = [s(t) x8][xl(t+1) x2][s(t+1) x8] ----
    for (int t = 0; t < 30; t += 2) {
        // even step t (buf0): +xl(t+2) -> wait 12 retires s(t) -> compute ->
        // wait 10 retires xl(t+1) -> xstore -> lgkm0 (ds_reads done before wstage
        // overwrites this wave's W region; ds_writes visible before barrier) -> wstage
        xloadA(t + 2);
        WAITV(12);
        compute(0);
        WAITV(10);
        xstore(1, xa1, xb1);          // data t+1 (odd -> set B)
        WAITL();
        wstage(0, t + 2);
        SBAR();
        // odd step t+1 (buf1)
        xloadB(t + 3);
        WAITV(12);
        compute(1);
        WAITV(10);
        xstore(0, xa0, xb0);          // data t+2 (even -> set A)
        WAITL();
        wstage(1, t + 3);
        SBAR();
    }
    // t = 30 (buf0): entry [s30 x8][xl31 x2][s31 x8]
    WAITV(10);                         // retires s30
    compute(0);
    WAITV(8);                          // retires xl31
    xstore(1, xa1, xb1);               // data 31 (set B)
    WAITL();
    SBAR();
    // t = 31 (buf1)
    WAITV(0);                          // retires s31
    compute(1);

    // merge split accumulators: c_hat = acc_m + acc_c
    #pragma unroll
    for (int i = 0; i < 4; i++)
        #pragma unroll
        for (int j = 0; j < 4; j++) accm[i][j] += accc[i][j];

    // ---- epilogue: shat, per-row min, margin mask ----
    // (scratch lives in buf0 bytes [0,3588); buf0 last read at t=30, behind a barrier)
    const int g  = lane >> 4;
    const int cl = lane & 15;
    float* minw = (float*)lds;                           // [64][4]   bytes [0,1024)
    unsigned short* m16 = (unsigned short*)(lds + 1024); // [64][16]  bytes [1024,3072)
    int* lidx   = (int*)(lds + 3072);                    // [64]      bytes [3072,3328)
    int* mlist  = (int*)(lds + 3328);                    // [64]      bytes [3328,3584)
    int* nmulti = (int*)(lds + 3584);                    // [1]

    float wsqv[4];
    #pragma unroll
    for (int jt = 0; jt < 4; jt++) wsqv[jt] = wsq[wv * 64 + jt * 16 + cl];

    float xsv[4][4], mv[4][4];
    #pragma unroll
    for (int rt = 0; rt < 4; rt++)
        #pragma unroll
        for (int e = 0; e < 4; e++) {
            const int r = row0 + rt * 16 + g * 4 + e;
            const float xs = xsq[r];
            xsv[rt][e] = xs;
            mv[rt][e] = 2.5e-6f * s1[r] + 6e-7f * (xs + 64.0f) + 1e-12f;
        }

    #pragma unroll
    for (int rt = 0; rt < 4; rt++)
        #pragma unroll
        for (int jt = 0; jt < 4; jt++)
            #pragma unroll
            for (int e = 0; e < 4; e++) {
                const float c = accm[rt][jt][e];
                const float t1 = xsv[rt][e] - 2.0f * c;
                accm[rt][jt][e] = t1 + wsqv[jt];      // shat, same rounding pipeline as exact path
            }

    #pragma unroll
    for (int rt = 0; rt < 4; rt++)
        #pragma unroll
        for (int e = 0; e < 4; e++) {
            float mn = fminf(fminf(accm[rt][0][e], accm[rt][1][e]), fminf(accm[rt][2][e], accm[rt][3][e]));
            #pragma unroll
            for (int m = 8; m; m >>= 1) mn = fminf(mn, __shfl_xor(mn, m, 64));
            if (cl == 0) minw[(rt * 16 + g * 4 + e) * 4 + wv] = mn;
        }
    __syncthreads();

    float tv[4][4];
    #pragma unroll
    for (int rt = 0; rt < 4; rt++)
        #pragma unroll
        for (int e = 0; e < 4; e++) {
            const int r = rt * 16 + g * 4 + e;
            const float gm = fminf(fminf(minw[r * 4 + 0], minw[r * 4 + 1]),
                                   fminf(minw[r * 4 + 2], minw[r * 4 + 3]));
            tv[rt][e] = gm + mv[rt][e];
        }
    #pragma unroll
    for (int rt = 0; rt < 4; rt++)
        #pragma unroll
        for (int jt = 0; jt < 4; jt++)
            #pragma unroll
            for (int e = 0; e < 4; e++) {
                const unsigned long long b = __ballot(accm[rt][jt][e] <= tv[rt][e]);
                if (cl == 0)
                    m16[(rt * 16 + g * 4 + e) * 16 + wv * 4 + jt] = (unsigned short)(b >> (g * 16));
            }
    __syncthreads();

    // wave 0: provisional argmin (lowest candidate) + compact multi-candidate row list
    if (wv == 0) {
        unsigned int mw[8];
        int cnt = 0;
        #pragma unroll
        for (int i = 0; i < 8; i++) {
            mw[i] = (unsigned int)m16[lane * 16 + 2 * i] | ((unsigned int)m16[lane * 16 + 2 * i + 1] << 16);
            cnt += __popc(mw[i]);
        }
        int kb = 0;
        #pragma unroll
        for (int i = 7; i >= 0; i--) if (mw[i]) kb = 32 * i + __ffs(mw[i]) - 1;   // lowest set bit
        lidx[lane] = kb;
        const unsigned long long act = __ballot(cnt > 1);
        if (cnt > 1) {
            const int pfx = __popcll(act & ((1ull << lane) - 1ull));
            mlist[pfx] = lane;
        }
        if (lane == 0) nmulti[0] = __popcll(act);
    }
    __syncthreads();

    // in-kernel exact resolve (fp64-quad pipeline, verbatim order + tie-break)
    const int nm = nmulti[0];
    for (int i = wv; i < nm; i += 4) {
        const int r = mlist[i];
        unsigned int mw[8];
        #pragma unroll
        for (int q = 0; q < 8; q++)
            mw[q] = (unsigned int)m16[r * 16 + 2 * q] | ((unsigned int)m16[r * 16 + 2 * q + 1] << 16);

        float4 xq[4];
        #pragma unroll
        for (int p = 0; p < 4; p++) {
            const int c = lane + 64 * p;
            xq[p] = (c < DIM / 4) ? *(const float4*)(x + (size_t)(row0 + r) * DIM + c * 4)
                                  : make_float4(0.f, 0.f, 0.f, 0.f);
        }
        const float xs = xsq[row0 + r];
        float bv = 3.4e38f; int bk = KCB;
        for (int wd = 0; wd < 8; wd++) {
            unsigned int m = mw[wd];
            while (m) {
                const int k = wd * 32 + __ffs(m) - 1;
                m &= m - 1;
                double a = 0.0;
                #pragma unroll
                for (int p = 0; p < 4; p++) {
                    const int c = lane + 64 * p;
                    if (c < DIM / 4) {
                        const float4 wq = *(const float4*)(w + (size_t)k * DIM + c * 4);
                        float pt = xq[p].x * wq.x;
                        pt = fmaf(xq[p].y, wq.y, pt);
                        pt = fmaf(xq[p].z, wq.z, pt);
                        pt = fmaf(xq[p].w, wq.w, pt);
                        a += (double)pt;
                    }
                }
                #pragma unroll
                for (int off = 32; off; off >>= 1) a += __shfl_xor(a, off, 64);
                const float c32 = (float)a;
                const float t1 = xs - 2.0f * c32;
                const float sv = t1 + wsq[k];
                if (sv < bv) { bv = sv; bk = k; }   // ascending k + strict < == lowest-index tiebreak
            }
        }
        if (lane == 0) lidx[r] = bk;
    }
    __syncthreads();

    // gather
    for (int r = wv; r < RBM; r += 4) {
        const int k = lidx[r];
        const float4* src = (const float4*)(w + (size_t)k * DIM);
        float4* dst = (float4*)(out + (size_t)(row0 + r) * DIM);
        for (int c = lane; c < DIM / 4; c += 64) dst[c] = src[c];
    }
}

extern "C" void kernel_launch(void* const* d_in, const int* in_sizes, int n_in,
                              void* d_out, int out_size, void* d_ws, size_t ws_size,
                              hipStream_t stream) {
    const float* x = (const float*)d_in[0];
    const float* w = (const float*)d_in[1];
    float* out  = (float*)d_out;
    float* base = (float*)d_ws;

    // workspace (words): wsq 256 | xsq 65536 | s1 65536 | whi 131072 | wlo 131072 = 393472
    const size_t NEED = 393472ull * 4ull;
    if (ws_size < NEED) {   // fallback: proven old path (needs only 257 KB)
        float* wsq = base;
        float* xsq = wsq + KCB;
        wsq_old_kernel<<<KCB / 4, 256, 0, stream>>>(w, wsq);
        xsq_old_kernel<<<N_ROWS / 4, 256, 0, stream>>>(x, xsq);
        vq_old_kernel<<<N_ROWS / RB, 256, 0, stream>>>(x, w, wsq, xsq, out);
        return;
    }

    float*          wsq = base;                                  // 256
    float*          xsq = base + 256;                            // 65536
    float*          s1  = base + 65792;                          // 65536
    unsigned short* whi = (unsigned short*)(base + 131328);      // 131072 words
    unsigned short* wlo = (unsigned short*)(base + 262400);      // 131072 words

    prep_kernel<<<KCB / 4, 256, 0, stream>>>(w, wsq, whi, wlo);
    xsq_s1_kernel<<<N_ROWS / 4, 256, 0, stream>>>(x, xsq, s1);
    vq_main_kernel<<<N_ROWS / RBM, 256, 0, stream>>>(x, w, wsq, xsq, s1, whi, wlo, out);
}